// Round 3
// baseline (317.841 us; speedup 1.0000x reference)
//
#include <hip/hip_runtime.h>

#define HH 512
#define WW 512
#define TILE 32
#define HALO 5
#define LT (TILE + 2 * HALO) /* 42 */
#define STR 43               /* LDS row stride in float4 */
#define PI_F 3.14159265358979323846f

// Depth-aware scatter (splat) bokeh as gather.
// out[b,c,y,x] = sum_disk [r(src)>=dist] g(src) rgb(src,c) / sum_disk [r(src)>=dist] g(src)
// Per source pixel we precompute rank = #{sorted dists <= r} (exact f32 compares
// against the input diskernel values) and pack it into g's low 4 mantissa bits,
// so the inner loop is ONE ds_read_b128 per source row, shared by a 1x4 output
// strip via a rolling window (no register buffering -> low VGPR).
__global__ __launch_bounds__(256, 4) void Scatter_Rendering_87101936763449_kernel(
    const float* __restrict__ x, const float* __restrict__ lens,
    const float* __restrict__ dk, float* __restrict__ out) {
    __shared__ float4 sg[LT * STR]; // (s0, s1, s2, g|rank)

    const int b  = blockIdx.z;
    const int bx = blockIdx.x * TILE;
    const int by = blockIdx.y * TILE;
    const int t  = threadIdx.x;

    const float le = lens[b];
    const float* xb = x + (size_t)b * 4 * HH * WW;

    // 14 distinct dist values in ascending order, read from the INPUT diskernel
    // (exact floats the reference compares against). d2 asc = dist asc.
    // d2:   0  1  2  4  5  8  9 10 13 16 17 18 20 25
    float dsort[14];
    {
        const int AA[14] = {0, 0, 1, 0, 1, 2, 0, 1, 2, 0, 1, 3, 2, 0};
        const int CC[14] = {0, 1, 1, 2, 2, 2, 3, 3, 3, 4, 4, 3, 4, 5};
#pragma unroll
        for (int k = 0; k < 14; ++k) dsort[k] = dk[(5 + AA[k]) * 11 + (5 + CC[k])];
    }

    // Stage 42x42 halo'd tile: one float4 per source pixel.
    for (int i = t; i < LT * LT; i += 256) {
        int ly = i / LT, lx = i - ly * LT;
        int gy = by + ly - HALO; gy = gy < 0 ? 0 : (gy > HH - 1 ? HH - 1 : gy);
        int gx = bx + lx - HALO; gx = gx < 0 ? 0 : (gx > WW - 1 ? WW - 1 : gx);
        int gi = gy * WW + gx;
        float d = xb[3 * HH * WW + gi];
        float r = fminf(fabsf(d) * le, (float)HALO);
        float g = 1.0f / (PI_F * r * r + 1.0f);
        int rank = 0;
#pragma unroll
        for (int k = 0; k < 14; ++k) rank += (r >= dsort[k]) ? 1 : 0; // exact coverage
        // rank in [0,14] -> low 4 mantissa bits of g (rel. perturbation <= 2^-19)
        float gm = __uint_as_float((__float_as_uint(g) & ~15u) | (unsigned)rank);
        sg[ly * STR + lx] = make_float4(xb[gi] * g, xb[HH * WW + gi] * g,
                                        xb[2 * HH * WW + gi] * g, gm);
    }

    __syncthreads();

    const int tx   = t & 31;
    const int yloc = (t >> 5) * 4; // this thread owns output rows yloc..yloc+3

    // Active di range per dj for the d2<=25 disk.
    const int DIMIN[11] = {5, 2, 1, 1, 1, 0, 1, 1, 1, 2, 5};
    const int DIMAX[11] = {5, 8, 9, 9, 9, 10, 9, 9, 9, 8, 5};
    // sorted position of each valid d2 (wm = rank > SP[d2])
    const int SP[26] = {0, 1, 2, -1, 3, 4, -1, -1, 5, 6, 7, -1, -1, 8, -1, -1,
                        9, 10, 11, -1, 12, -1, -1, -1, -1, 13};

    float acc[4][4] = {{0.f}}; // [p][{r,g,b,den}], all indices static after unroll

#pragma unroll
    for (int dj = 0; dj < 11; ++dj) {
        const int lo = DIMIN[dj], hi = DIMAX[dj];
#pragma unroll
        for (int k = lo; k <= hi + 3; ++k) { // rolling: row k serves px p at di=k-p
            const float4 v = sg[(yloc + k) * STR + (tx + dj)];
            const int rk = (int)(__float_as_uint(v.w) & 15u);
#pragma unroll
            for (int p = 0; p < 4; ++p) {
                const int di = k - p;
                if (di < lo || di > hi) continue;
                const int d2 = (di - 5) * (di - 5) + (dj - 5) * (dj - 5);
                const float wm = (rk > SP[d2]) ? 1.0f : 0.0f;
                acc[p][0] = fmaf(wm, v.x, acc[p][0]);
                acc[p][1] = fmaf(wm, v.y, acc[p][1]);
                acc[p][2] = fmaf(wm, v.z, acc[p][2]);
                acc[p][3] = fmaf(wm, v.w, acc[p][3]);
            }
        }
    }

#pragma unroll
    for (int p = 0; p < 4; ++p) {
        const float inv = 1.0f / acc[p][3];
        const size_t o = (size_t)b * 3 * HH * WW + (size_t)(by + yloc + p) * WW + (bx + tx);
        out[o]               = acc[p][0] * inv;
        out[o + HH * WW]     = acc[p][1] * inv;
        out[o + 2 * HH * WW] = acc[p][2] * inv;
    }
}

extern "C" void kernel_launch(void* const* d_in, const int* in_sizes, int n_in,
                              void* d_out, int out_size, void* d_ws, size_t ws_size,
                              hipStream_t stream) {
    const float* x    = (const float*)d_in[0]; // (4,4,512,512)
    const float* lens = (const float*)d_in[1]; // (4,1)
    const float* dk   = (const float*)d_in[2]; // (11,11)
    float* out = (float*)d_out;                // (4,3,512,512)

    dim3 grid(WW / TILE, HH / TILE, 4);        // 16x16x4 = 1024 blocks (4/CU)
    dim3 block(256);
    hipLaunchKernelGGL(Scatter_Rendering_87101936763449_kernel, grid, block, 0, stream,
                       x, lens, dk, out);
}